// Round 8
// baseline (250.443 us; speedup 1.0000x reference)
//
#include <hip/hip_runtime.h>
#include <hip/hip_bf16.h>
#include <math.h>

// EmbeddingAlignerOT on MI355X.
// R8: BK back to 32 (R7's BK=64 regressed: conflicts x3, occupancy down).
// GEMM1 stages A DIRECTLY from src fp32 (f32 LDS tile, bf16 cast at
// fragment read) -> the 128MB src cvt pass is gone. W still pre-cvt (4MB).
// Workspace: [0,16M) Kmat | [16M,32M) KTmat | [32M,34M) W_bf + ua/ub/va/vb
// after gemm1 | [34M,66M) g_bf | [66M,98M) t_bf -> gTv | [98M..) scalars.

typedef __bf16 bf16_t;
typedef __bf16 bf16x8 __attribute__((ext_vector_type(8)));
typedef float  f32x4  __attribute__((ext_vector_type(4)));

#define NBATCH 32
#define NS 512
#define NG 512
#define NH 1024
#define M_REAL 3
#define N_TOT 100

__device__ __forceinline__ void async_copy16(const void* gsrc, void* ldst) {
  __builtin_amdgcn_global_load_lds(
      (__attribute__((address_space(1))) void*)gsrc,
      (__attribute__((address_space(3))) void*)ldst, 16, 0, 0);
}

// ---------- fp32 -> bf16 convert (W only now) ----------
__global__ __launch_bounds__(256) void cvt_bf16_kernel(const float* __restrict__ in,
                                                       bf16_t* __restrict__ out, int n8) {
  int i = blockIdx.x * 256 + threadIdx.x;
  if (i >= n8) return;
  const float4* p = (const float4*)in + (size_t)i * 2;
  float4 a = p[0], b = p[1];
  bf16x8 o;
  o[0] = (__bf16)a.x; o[1] = (__bf16)a.y; o[2] = (__bf16)a.z; o[3] = (__bf16)a.w;
  o[4] = (__bf16)b.x; o[5] = (__bf16)b.y; o[6] = (__bf16)b.z; o[7] = (__bf16)b.w;
  ((bf16x8*)out)[i] = o;
}

// ---------- target: convert to bf16 + fp32 row norms ----------
__global__ __launch_bounds__(128) void prep_g_kernel(const float* __restrict__ g,
                                                     bf16_t* __restrict__ gb,
                                                     float* __restrict__ g2) {
  int row = blockIdx.x;   // B*G rows of length NH
  int t = threadIdx.x;    // 128
  const float* rp = g + (size_t)row * NH + t * 8;
  float4 a = *(const float4*)rp;
  float4 b = *(const float4*)(rp + 4);
  bf16x8 o;
  o[0] = (__bf16)a.x; o[1] = (__bf16)a.y; o[2] = (__bf16)a.z; o[3] = (__bf16)a.w;
  o[4] = (__bf16)b.x; o[5] = (__bf16)b.y; o[6] = (__bf16)b.z; o[7] = (__bf16)b.w;
  ((bf16x8*)(gb + (size_t)row * NH))[t] = o;
  float ss = a.x*a.x + a.y*a.y + a.z*a.z + a.w*a.w
           + b.x*b.x + b.y*b.y + b.z*b.z + b.w*b.w;
  #pragma unroll
  for (int ofs = 32; ofs > 0; ofs >>= 1) ss += __shfl_down(ss, ofs);
  __shared__ float wsum[2];
  if ((t & 63) == 0) wsum[t >> 6] = ss;
  __syncthreads();
  if (t == 0) g2[row] = wsum[0] + wsum[1];
}

// ---------- adjusted weights for BOTH sides in one dispatch ----------
__global__ __launch_bounds__(512) void weights2_kernel(
    const float* __restrict__ s2, const int* __restrict__ smask, float* __restrict__ swv,
    const float* __restrict__ g2, const int* __restrict__ gmask, float* __restrict__ gwv) {
  int which = blockIdx.x >> 5;
  int bb = blockIdx.x & 31, t = threadIdx.x;
  const float* n2 = which ? g2 : s2;
  const int* mask = which ? gmask : smask;
  float* wout = which ? gwv : swv;
  int idx = bb * 512 + t;
  float mag = sqrtf(n2[idx]) + 1e-12f;
  float w = (float)mask[idx] * mag + 1e-12f;
  float ss = w;
  #pragma unroll
  for (int ofs = 32; ofs > 0; ofs >>= 1) ss += __shfl_down(ss, ofs);
  __shared__ float red[8];
  __shared__ float tot;
  if ((t & 63) == 0) red[t >> 6] = ss;
  __syncthreads();
  if (t == 0) {
    float x = 0.f;
    #pragma unroll
    for (int i = 0; i < 8; i++) x += red[i];
    tot = fmaxf(x, 1e-12f);
  }
  __syncthreads();
  wout[idx] = w / tot;
}

// ---------- C = A * B^T, 128x128 tile, BK=32, 4 waves, bf16 MFMA ----------
// XCD-aware bijective swizzle (1-D grid, nwg%8==0).
// MODE 0: A staged as RAW FP32 (16KB LDS tile), cast to bf16 at fragment
//         read (identical bf16 bits vs pre-converting). B = W_bf (bf16).
//         t = A@B^T + bias, bf16 store; fused row-norm atomicAdd -> s2out.
// MODE 1: bf16 A,B. K = exp(-10*(sqrt(s2+g2-2C)*sw*gw+eps)), bf16 (batched)
// MODE 2: bf16 A,B. out = u .* C, fp32 store (batched)
template <int MODE, int GX, int GY>
__global__ __launch_bounds__(256) void gemm_bt_kernel(
    const void* __restrict__ A, const bf16_t* __restrict__ Bm, int K_len,
    size_t strideAb, size_t strideBb,
    void* __restrict__ outp, size_t strideOb, int ldc,
    const float* __restrict__ bias,
    const float* __restrict__ s2, const float* __restrict__ g2,
    const float* __restrict__ sw, const float* __restrict__ gw,
    const float* __restrict__ uvec, float* __restrict__ s2out) {
  __shared__ char smem[MODE == 0 ? 24576 : 16384];
  const int nwg = gridDim.x;
  const int lin = blockIdx.x;
  const int lin2 = (lin & 7) * (nwg >> 3) + (lin >> 3);
  const int bx = lin2 % GX;
  const int by = (lin2 / GX) % GY;
  const int bz = lin2 / (GX * GY);
  const int tid = threadIdx.x, lane = tid & 63, wave = tid >> 6;
  const int wr = wave >> 1, wc = wave & 1;
  const int m0 = by * 128, n0 = bx * 128;

  float* lAf = (float*)smem;                                    // MODE0: 16KB
  bf16_t* lA = (bf16_t*)smem;                                   // MODE1/2: 8KB
  bf16_t* lB = (bf16_t*)(smem + (MODE == 0 ? 16384 : 8192));    // 8KB

  const float* Af = (const float*)A;                            // MODE0
  const bf16_t* Ab = (const bf16_t*)A + (size_t)bz * strideAb;  // MODE1/2
  const bf16_t* Bb = Bm + (size_t)bz * strideBb;

  // bf16 staging coords: 16-row groups, lane covers 8 bf16 (16B)
  const int rA16 = lane >> 2, c8 = (lane & 3) * 8;
  // f32 staging coords: 8-row groups, lane covers 4 f32 (16B)
  const int rA8 = lane >> 3, c4 = (lane & 7) * 4;

  f32x4 acc[4][4];
  #pragma unroll
  for (int i = 0; i < 4; i++)
    #pragma unroll
    for (int j = 0; j < 4; j++) { f32x4 z = {0.f, 0.f, 0.f, 0.f}; acc[i][j] = z; }

  for (int kt = 0; kt < K_len; kt += 32) {
    if (kt) __syncthreads();
    if (MODE == 0) {
      #pragma unroll
      for (int c = 0; c < 4; c++) {     // A: 128x32 f32, 4 issues of 32 rows
        int rg = (c * 4 + wave) * 8;
        async_copy16(Af + (size_t)(m0 + rg + rA8) * K_len + kt + c4, &lAf[rg * 32]);
      }
      #pragma unroll
      for (int c = 0; c < 2; c++) {     // B: 128x32 bf16, 2 issues of 64 rows
        int rg = (c * 4 + wave) * 16;
        async_copy16(Bb + (size_t)(n0 + rg + rA16) * K_len + kt + c8, &lB[rg * 32]);
      }
    } else {
      #pragma unroll
      for (int c = 0; c < 2; c++) {
        int rg = (c * 4 + wave) * 16;
        async_copy16(Ab + (size_t)(m0 + rg + rA16) * K_len + kt + c8, &lA[rg * 32]);
        async_copy16(Bb + (size_t)(n0 + rg + rA16) * K_len + kt + c8, &lB[rg * 32]);
      }
    }
    __syncthreads();  // compiler drains vmcnt(0) before barrier
    bf16x8 af[4], bf[4];
    #pragma unroll
    for (int m = 0; m < 4; m++) {
      if (MODE == 0) {
        const float* rp = &lAf[(wr * 64 + m * 16 + (lane & 15)) * 32 + (lane >> 4) * 8];
        f32x4 a0 = *(const f32x4*)rp;
        f32x4 a1 = *(const f32x4*)(rp + 4);
        af[m][0] = (__bf16)a0[0]; af[m][1] = (__bf16)a0[1];
        af[m][2] = (__bf16)a0[2]; af[m][3] = (__bf16)a0[3];
        af[m][4] = (__bf16)a1[0]; af[m][5] = (__bf16)a1[1];
        af[m][6] = (__bf16)a1[2]; af[m][7] = (__bf16)a1[3];
      } else {
        af[m] = *(const bf16x8*)&lA[(wr * 64 + m * 16 + (lane & 15)) * 32 + (lane >> 4) * 8];
      }
    }
    #pragma unroll
    for (int n = 0; n < 4; n++)
      bf[n] = *(const bf16x8*)&lB[(wc * 64 + n * 16 + (lane & 15)) * 32 + (lane >> 4) * 8];
    #pragma unroll
    for (int m = 0; m < 4; m++)
      #pragma unroll
      for (int n = 0; n < 4; n++)
        acc[m][n] = __builtin_amdgcn_mfma_f32_16x16x32_bf16(af[m], bf[n], acc[m][n], 0, 0, 0);
  }

  // epilogue: C/D frag mapping col=lane&15, row=(lane>>4)*4+j
  const int bo = bz * 512;
  const int row_base = m0 + wr * 64, col_base = n0 + wc * 64;
  const int r_off = (lane >> 4) * 4, c_off = lane & 15;
  float p[4][4];
  #pragma unroll
  for (int m = 0; m < 4; m++)
    #pragma unroll
    for (int j = 0; j < 4; j++) p[m][j] = 0.f;

  #pragma unroll
  for (int m = 0; m < 4; m++) {
    #pragma unroll
    for (int n = 0; n < 4; n++) {
      #pragma unroll
      for (int j = 0; j < 4; j++) {
        int gm = row_base + m * 16 + r_off + j;
        int gn = col_base + n * 16 + c_off;
        float val = acc[m][n][j];
        if (MODE == 0) {
          float tv = val + bias[gn];
          ((bf16_t*)outp)[(size_t)gm * ldc + gn] = (__bf16)tv;
          p[m][j] += tv * tv;
        } else if (MODE == 1) {
          float sq = s2[bo + gm] + g2[bo + gn] - 2.0f * val;
          float d = sqrtf(fmaxf(sq, 0.0f));
          float cost = d * sw[bo + gm] * gw[bo + gn] + 1e-12f;
          ((bf16_t*)outp + (size_t)bz * strideOb)[(size_t)gm * ldc + gn] =
              (__bf16)expf(-10.0f * cost);
        } else {
          ((float*)outp + (size_t)bz * strideOb)[(size_t)gm * ldc + gn] =
              uvec[bo + gm] * val;
        }
      }
    }
  }

  if (MODE == 0) {
    // reduce (val+bias)^2 across the 128 cols this block owns -> atomicAdd s2out
    __syncthreads();
    float* lRed = (float*)smem;    // 128 floats
    #pragma unroll
    for (int m = 0; m < 4; m++)
      #pragma unroll
      for (int j = 0; j < 4; j++) {
        float v = p[m][j];
        v += __shfl_xor(v, 1);
        v += __shfl_xor(v, 2);
        v += __shfl_xor(v, 4);
        v += __shfl_xor(v, 8);
        p[m][j] = v;               // valid at lanes with (lane&15)==0
      }
    int rl = wr * 64 + (lane >> 4) * 4;
    if (wc == 0 && (lane & 15) == 0) {
      #pragma unroll
      for (int m = 0; m < 4; m++)
        #pragma unroll
        for (int j = 0; j < 4; j++) lRed[rl + m * 16 + j] = p[m][j];
    }
    __syncthreads();
    if (wc == 1 && (lane & 15) == 0) {
      #pragma unroll
      for (int m = 0; m < 4; m++)
        #pragma unroll
        for (int j = 0; j < 4; j++)
          atomicAdd(&s2out[m0 + rl + m * 16 + j], lRed[rl + m * 16 + j] + p[m][j]);
    }
  }
}

// ---------- wide transpose: out[c][r] = in[r][c] * (SCALE ? v[r] : 1) ----------
template <int SCALE>
__global__ __launch_bounds__(256) void wide_transpose_kernel(
    const bf16_t* __restrict__ in, bf16_t* __restrict__ out,
    const float* __restrict__ vscale, int inRows, int inCols) {
  __shared__ bf16_t tl[32][66];
  size_t base = (size_t)blockIdx.z * inRows * inCols;
  int r0 = blockIdx.y * 32, c0 = blockIdx.x * 64;
  int row = threadIdx.x >> 3, cc8 = (threadIdx.x & 7) * 8;
  *(bf16x8*)&tl[row][cc8] =
      *(const bf16x8*)(in + base + (size_t)(r0 + row) * inCols + c0 + cc8);
  __syncthreads();
  int orow = threadIdx.x >> 2;
  int rq = (threadIdx.x & 3) * 8;
  bf16x8 o;
  if (SCALE) {
    const float* vp = vscale + (size_t)blockIdx.z * inRows + r0 + rq;
    float4 va = *(const float4*)vp;
    float4 vb = *(const float4*)(vp + 4);
    o[0] = (__bf16)((float)tl[rq + 0][orow] * va.x);
    o[1] = (__bf16)((float)tl[rq + 1][orow] * va.y);
    o[2] = (__bf16)((float)tl[rq + 2][orow] * va.z);
    o[3] = (__bf16)((float)tl[rq + 3][orow] * va.w);
    o[4] = (__bf16)((float)tl[rq + 4][orow] * vb.x);
    o[5] = (__bf16)((float)tl[rq + 5][orow] * vb.y);
    o[6] = (__bf16)((float)tl[rq + 6][orow] * vb.z);
    o[7] = (__bf16)((float)tl[rq + 7][orow] * vb.w);
  } else {
    #pragma unroll
    for (int i = 0; i < 8; i++) o[i] = tl[rq + i][orow];
  }
  *(bf16x8*)(out + base + (size_t)(c0 + orow) * inRows + r0 + rq) = o;
}

// ---------- Sinkhorn half-iteration, grid-wide ----------
template <int INIT>
__global__ __launch_bounds__(256) void sink_pass_kernel(
    const bf16_t* __restrict__ Mmat, const float* __restrict__ x,
    const float* __restrict__ w, float* __restrict__ y) {
  const int b = blockIdx.y;
  const int t = threadIdx.x;
  __shared__ float xs[512];
  if (!INIT) {
    ((float2*)xs)[t] = ((const float2*)(x + b * 512))[t];
    __syncthreads();
  }
  const int row = blockIdx.x * 64 + (t >> 2);
  const int seg = t & 3;
  const bf16_t* rp = Mmat + ((size_t)b * 512 + row) * 512;
  float sum = 0.f;
  #pragma unroll
  for (int j = 0; j < 16; j++) {
    bf16x8 kv = *(const bf16x8*)(rp + seg * 8 + j * 32);
    if (INIT) {
      sum += (float)kv[0] + (float)kv[1] + (float)kv[2] + (float)kv[3] +
             (float)kv[4] + (float)kv[5] + (float)kv[6] + (float)kv[7];
    } else {
      const float4* xp = (const float4*)&xs[seg * 8 + j * 32];
      float4 x0 = xp[0], x1 = xp[1];
      sum += (float)kv[0] * x0.x + (float)kv[1] * x0.y + (float)kv[2] * x0.z +
             (float)kv[3] * x0.w + (float)kv[4] * x1.x + (float)kv[5] * x1.y +
             (float)kv[6] * x1.z + (float)kv[7] * x1.w;
    }
  }
  if (INIT) sum *= (1.0f / 512.0f);
  sum += __shfl_xor(sum, 1);
  sum += __shfl_xor(sum, 2);
  if (seg == 0)
    y[b * 512 + row] = powf(w[b * 512 + row] / sum, 10.0f / 10.1f);
}

// ---------- Sinkhorn closed-form extrapolation to iteration 100 ----------
// args: (prev u, curr u, prev v, curr v); x_100 = x_M * exp(rho_M * G)
__global__ __launch_bounds__(512) void sink_final_kernel(
    const float* __restrict__ ua, const float* __restrict__ ub,
    const float* __restrict__ va, const float* __restrict__ vb,
    float* __restrict__ u_out, float* __restrict__ v_out, float Gf) {
  const int b = blockIdx.x, t = threadIdx.x, idx = b * 512 + t;
  const float ubv = ub[idx], vbv = vb[idx];
  float su = logf(ubv / ua[idx]);
  float sv = logf(vbv / va[idx]);
  #pragma unroll
  for (int ofs = 32; ofs > 0; ofs >>= 1) {
    su += __shfl_down(su, ofs);
    sv += __shfl_down(sv, ofs);
  }
  __shared__ float r0[8], r1[8];
  __shared__ float mu, mv;
  if ((t & 63) == 0) { r0[t >> 6] = su; r1[t >> 6] = sv; }
  __syncthreads();
  if (t == 0) {
    float a = 0.f, c = 0.f;
    #pragma unroll
    for (int i = 0; i < 8; i++) { a += r0[i]; c += r1[i]; }
    mu = a / 512.f; mv = c / 512.f;
  }
  __syncthreads();
  u_out[idx] = ubv * expf(Gf * mu);
  v_out[idx] = vbv * expf(Gf * mv);
}

extern "C" void kernel_launch(void* const* d_in, const int* in_sizes, int n_in,
                              void* d_out, int out_size, void* d_ws, size_t ws_size,
                              hipStream_t stream) {
  (void)in_sizes; (void)n_in; (void)out_size; (void)ws_size;
  const float* src = (const float*)d_in[0];   // [32,512,1024]
  const float* tgt = (const float*)d_in[1];   // [32,512,1024]
  const int* smask = (const int*)d_in[2];     // [32,512]
  const int* gmask = (const int*)d_in[3];     // [32,512]
  const float* W   = (const float*)d_in[4];   // [1024,1024]
  const float* bias = (const float*)d_in[5];  // [1024]
  float* out = (float*)d_out;                 // [32,512,1024]

  uint8_t* ws = (uint8_t*)d_ws;
  bf16_t* Kmat  = (bf16_t*)(ws + 0);          // 16 MB
  bf16_t* KTmat = (bf16_t*)(ws + 16777216);   // 16 MB
  bf16_t* W_bf  = (bf16_t*)(ws + 33554432);   // 2 MB
  float* ua = (float*)(ws + 33554432);        // overwrite W_bf after gemm1
  float* ub = ua + 16384;
  float* va = ub + 16384;
  float* vb = va + 16384;
  bf16_t* g_bf  = (bf16_t*)(ws + 35651584);   // 32 MB
  bf16_t* t_bf  = (bf16_t*)(ws + 69206016);   // 32 MB
  bf16_t* gTv   = (bf16_t*)(ws + 69206016);   // reuse after gemm2
  float* s2  = (float*)(ws + 102760448);
  float* g2  = s2 + 16384;
  float* swv = g2 + 16384;
  float* gwv = swv + 16384;
  float* uv  = gwv + 16384;
  float* vv  = uv + 16384;

  // 1. W cvt + g prep (cvt+norms); zero s2 for fused-norm atomics
  cvt_bf16_kernel<<<512, 256, 0, stream>>>(W, W_bf, 131072);
  prep_g_kernel<<<16384, 128, 0, stream>>>(tgt, g_bf, g2);
  hipMemsetAsync(s2, 0, 16384 * sizeof(float), stream);

  // 2. t = src(fp32) @ W_bf^T + b + fused row norms -> s2
  gemm_bt_kernel<0, 8, 128><<<1024, 256, 0, stream>>>(
      src, W_bf, 1024, 0, 0, t_bf, 0, 1024, bias,
      nullptr, nullptr, nullptr, nullptr, nullptr, s2);

  // 3. weights (both sides, one dispatch)
  weights2_kernel<<<64, 512, 0, stream>>>(s2, smask, swv, g2, gmask, gwv);

  // 4. K = exp(-10*cost)  (per batch 512x512, K=1024)
  gemm_bt_kernel<1, 4, 4><<<512, 256, 0, stream>>>(
      t_bf, g_bf, 1024, (size_t)512 * 1024, (size_t)512 * 1024,
      Kmat, (size_t)512 * 512, 512, nullptr, s2, g2, swv, gwv, nullptr, nullptr);

  // 5. K^T (wide transpose)
  wide_transpose_kernel<0><<<dim3(8, 16, 32), 256, 0, stream>>>(
      Kmat, KTmat, nullptr, NS, NG);

  // 6. Sinkhorn: 3 real iterations (6 passes) + extrapolation.
  // u1->ua v1->va u2->ub v2->vb u3->ua v3->va; ratios (prev=ub,curr=ua) etc.
  dim3 pg(NS / 64, NBATCH);
  sink_pass_kernel<1><<<pg, 256, 0, stream>>>(Kmat, nullptr, swv, ua);   // u1
  sink_pass_kernel<0><<<pg, 256, 0, stream>>>(KTmat, ua, gwv, va);       // v1
  sink_pass_kernel<0><<<pg, 256, 0, stream>>>(Kmat, va, swv, ub);        // u2
  sink_pass_kernel<0><<<pg, 256, 0, stream>>>(KTmat, ub, gwv, vb);       // v2
  sink_pass_kernel<0><<<pg, 256, 0, stream>>>(Kmat, vb, swv, ua);        // u3
  sink_pass_kernel<0><<<pg, 256, 0, stream>>>(KTmat, ua, gwv, va);       // v3

  // G = sum_{j=1}^{100-M_REAL} fi^(2j) in double
  double fi2 = (10.0 / 10.1) * (10.0 / 10.1);
  double Gd = 0.0, pd = 1.0;
  for (int j = 0; j < (N_TOT - M_REAL); j++) { pd *= fi2; Gd += pd; }
  sink_final_kernel<<<32, 512, 0, stream>>>(ub, ua, vb, va, uv, vv, (float)Gd);

  // 7. gTv[h][g] = v[g]*g[g][h] (wide transpose + scale)
  wide_transpose_kernel<1><<<dim3(16, 16, 32), 256, 0, stream>>>(
      g_bf, gTv, vv, NG, NH);

  // 8. aligned = u .* (K @ gTv)  (per batch 512x1024, K=512)
  gemm_bt_kernel<2, 8, 4><<<1024, 256, 0, stream>>>(
      Kmat, gTv, 512, (size_t)512 * 512, (size_t)1024 * 512,
      out, (size_t)512 * 1024, 1024, nullptr, nullptr, nullptr, nullptr, nullptr, uv, nullptr);
}

// Round 9
// 224.528 us; speedup vs baseline: 1.1154x; 1.1154x over previous
//
#include <hip/hip_runtime.h>
#include <hip/hip_bf16.h>
#include <math.h>

// EmbeddingAlignerOT on MI355X.
// R9: revert GEMM inner loop to R6's BK=32 bf16-staged form (R7 BK=64 and
// R8 f32-staging both regressed: bank conflicts). Keep R7's wins: merged
// cvt2, norm_t fused into GEMM1 epilogue, weights2, M_REAL=3, wide transposes.
// Workspace (~103.2 MB): [0,32M) s_bf -> K+KT after gemm1 | [32M,34M) W_bf ->
// ua/ub/va/vb | [34M,66M) g_bf | [66M,98M) t_bf -> gTv | [98M..) scalars.

typedef __bf16 bf16_t;
typedef __bf16 bf16x8 __attribute__((ext_vector_type(8)));
typedef float  f32x4  __attribute__((ext_vector_type(4)));

#define NBATCH 32
#define NS 512
#define NG 512
#define NH 1024
#define M_REAL 3
#define N_TOT 100

__device__ __forceinline__ void async_copy16(const void* gsrc, void* ldst) {
  __builtin_amdgcn_global_load_lds(
      (__attribute__((address_space(1))) void*)gsrc,
      (__attribute__((address_space(3))) void*)ldst, 16, 0, 0);
}

// ---------- fp32 -> bf16 convert, src and W in one dispatch ----------
__global__ __launch_bounds__(256) void cvt2_kernel(const float* __restrict__ a,
                                                   bf16_t* __restrict__ outa, int n8a,
                                                   const float* __restrict__ b,
                                                   bf16_t* __restrict__ outb) {
  int i = blockIdx.x * 256 + threadIdx.x;
  const float* src;
  bf16_t* dst;
  int idx;
  if (i < n8a) { src = a; dst = outa; idx = i; }
  else         { src = b; dst = outb; idx = i - n8a; }
  const float4* p = (const float4*)src + (size_t)idx * 2;
  float4 x = p[0], y = p[1];
  bf16x8 o;
  o[0] = (__bf16)x.x; o[1] = (__bf16)x.y; o[2] = (__bf16)x.z; o[3] = (__bf16)x.w;
  o[4] = (__bf16)y.x; o[5] = (__bf16)y.y; o[6] = (__bf16)y.z; o[7] = (__bf16)y.w;
  ((bf16x8*)dst)[idx] = o;
}

// ---------- target: convert to bf16 + fp32 row norms ----------
__global__ __launch_bounds__(128) void prep_g_kernel(const float* __restrict__ g,
                                                     bf16_t* __restrict__ gb,
                                                     float* __restrict__ g2) {
  int row = blockIdx.x;   // B*G rows of length NH
  int t = threadIdx.x;    // 128
  const float* rp = g + (size_t)row * NH + t * 8;
  float4 a = *(const float4*)rp;
  float4 b = *(const float4*)(rp + 4);
  bf16x8 o;
  o[0] = (__bf16)a.x; o[1] = (__bf16)a.y; o[2] = (__bf16)a.z; o[3] = (__bf16)a.w;
  o[4] = (__bf16)b.x; o[5] = (__bf16)b.y; o[6] = (__bf16)b.z; o[7] = (__bf16)b.w;
  ((bf16x8*)(gb + (size_t)row * NH))[t] = o;
  float ss = a.x*a.x + a.y*a.y + a.z*a.z + a.w*a.w
           + b.x*b.x + b.y*b.y + b.z*b.z + b.w*b.w;
  #pragma unroll
  for (int ofs = 32; ofs > 0; ofs >>= 1) ss += __shfl_down(ss, ofs);
  __shared__ float wsum[2];
  if ((t & 63) == 0) wsum[t >> 6] = ss;
  __syncthreads();
  if (t == 0) g2[row] = wsum[0] + wsum[1];
}

// ---------- adjusted weights for BOTH sides in one dispatch ----------
__global__ __launch_bounds__(512) void weights2_kernel(
    const float* __restrict__ s2, const int* __restrict__ smask, float* __restrict__ swv,
    const float* __restrict__ g2, const int* __restrict__ gmask, float* __restrict__ gwv) {
  int which = blockIdx.x >> 5;
  int bb = blockIdx.x & 31, t = threadIdx.x;
  const float* n2 = which ? g2 : s2;
  const int* mask = which ? gmask : smask;
  float* wout = which ? gwv : swv;
  int idx = bb * 512 + t;
  float mag = sqrtf(n2[idx]) + 1e-12f;
  float w = (float)mask[idx] * mag + 1e-12f;
  float ss = w;
  #pragma unroll
  for (int ofs = 32; ofs > 0; ofs >>= 1) ss += __shfl_down(ss, ofs);
  __shared__ float red[8];
  __shared__ float tot;
  if ((t & 63) == 0) red[t >> 6] = ss;
  __syncthreads();
  if (t == 0) {
    float x = 0.f;
    #pragma unroll
    for (int i = 0; i < 8; i++) x += red[i];
    tot = fmaxf(x, 1e-12f);
  }
  __syncthreads();
  wout[idx] = w / tot;
}

// ---------- C = A * B^T, 128x128 tile, BK=32, 4 waves, bf16 MFMA ----------
// XCD-aware bijective swizzle (1-D grid, nwg%8==0).
// MODE 0: t = A@B^T + bias, bf16 store; fused row-norm atomicAdd into s2out
// MODE 1: K = exp(-10*(sqrt(s2+g2-2C)*sw*gw+eps)) bf16 store (batched)
// MODE 2: out = u .* C, fp32 store (batched)
template <int MODE, int GX, int GY>
__global__ __launch_bounds__(256) void gemm_bt_kernel(
    const bf16_t* __restrict__ A, const bf16_t* __restrict__ Bm, int K_len,
    size_t strideAb, size_t strideBb,
    void* __restrict__ outp, size_t strideOb, int ldc,
    const float* __restrict__ bias,
    const float* __restrict__ s2, const float* __restrict__ g2,
    const float* __restrict__ sw, const float* __restrict__ gw,
    const float* __restrict__ uvec, float* __restrict__ s2out) {
  __shared__ bf16_t lA[128 * 32];
  __shared__ bf16_t lB[128 * 32];
  const int nwg = gridDim.x;
  const int lin = blockIdx.x;
  const int lin2 = (lin & 7) * (nwg >> 3) + (lin >> 3);
  const int bx = lin2 % GX;
  const int by = (lin2 / GX) % GY;
  const int bz = lin2 / (GX * GY);
  const int tid = threadIdx.x, lane = tid & 63, wave = tid >> 6;
  const int wr = wave >> 1, wc = wave & 1;
  const bf16_t* Ab = A + (size_t)bz * strideAb;
  const bf16_t* Bb = Bm + (size_t)bz * strideBb;
  const int m0 = by * 128, n0 = bx * 128;
  const int rA = lane >> 2;       // row within 16-row staging group
  const int c8 = (lane & 3) * 8;  // bf16 col offset of this lane's 16B chunk

  f32x4 acc[4][4];
  #pragma unroll
  for (int i = 0; i < 4; i++)
    #pragma unroll
    for (int j = 0; j < 4; j++) { f32x4 z = {0.f, 0.f, 0.f, 0.f}; acc[i][j] = z; }

  for (int kt = 0; kt < K_len; kt += 32) {
    if (kt) __syncthreads();
    #pragma unroll
    for (int c = 0; c < 2; c++) {
      int rg = (c * 4 + wave) * 16;
      async_copy16(Ab + (size_t)(m0 + rg + rA) * K_len + kt + c8, &lA[rg * 32]);
      async_copy16(Bb + (size_t)(n0 + rg + rA) * K_len + kt + c8, &lB[rg * 32]);
    }
    __syncthreads();  // compiler drains vmcnt(0) before barrier
    bf16x8 af[4], bf[4];
    #pragma unroll
    for (int m = 0; m < 4; m++)
      af[m] = *(const bf16x8*)&lA[(wr * 64 + m * 16 + (lane & 15)) * 32 + (lane >> 4) * 8];
    #pragma unroll
    for (int n = 0; n < 4; n++)
      bf[n] = *(const bf16x8*)&lB[(wc * 64 + n * 16 + (lane & 15)) * 32 + (lane >> 4) * 8];
    #pragma unroll
    for (int m = 0; m < 4; m++)
      #pragma unroll
      for (int n = 0; n < 4; n++)
        acc[m][n] = __builtin_amdgcn_mfma_f32_16x16x32_bf16(af[m], bf[n], acc[m][n], 0, 0, 0);
  }

  // epilogue: C/D frag mapping col=lane&15, row=(lane>>4)*4+j
  const int bo = bz * 512;
  const int row_base = m0 + wr * 64, col_base = n0 + wc * 64;
  const int r_off = (lane >> 4) * 4, c_off = lane & 15;
  float p[4][4];   // MODE0: per-thread row partial sums of (val+bias)^2
  #pragma unroll
  for (int m = 0; m < 4; m++)
    #pragma unroll
    for (int j = 0; j < 4; j++) p[m][j] = 0.f;

  #pragma unroll
  for (int m = 0; m < 4; m++) {
    #pragma unroll
    for (int n = 0; n < 4; n++) {
      #pragma unroll
      for (int j = 0; j < 4; j++) {
        int gm = row_base + m * 16 + r_off + j;
        int gn = col_base + n * 16 + c_off;
        float val = acc[m][n][j];
        if (MODE == 0) {
          float tv = val + bias[gn];
          ((bf16_t*)outp)[(size_t)gm * ldc + gn] = (__bf16)tv;
          p[m][j] += tv * tv;
        } else if (MODE == 1) {
          float sq = s2[bo + gm] + g2[bo + gn] - 2.0f * val;
          float d = sqrtf(fmaxf(sq, 0.0f));
          float cost = d * sw[bo + gm] * gw[bo + gn] + 1e-12f;
          ((bf16_t*)outp + (size_t)bz * strideOb)[(size_t)gm * ldc + gn] =
              (__bf16)expf(-10.0f * cost);
        } else {
          ((float*)outp + (size_t)bz * strideOb)[(size_t)gm * ldc + gn] =
              uvec[bo + gm] * val;
        }
      }
    }
  }

  if (MODE == 0) {
    // reduce (val+bias)^2 across the 128 cols this block owns -> atomicAdd s2out
    __syncthreads();               // all LDS reads done; reuse lA
    float* lRed = (float*)lA;      // 128 floats
    #pragma unroll
    for (int m = 0; m < 4; m++)
      #pragma unroll
      for (int j = 0; j < 4; j++) {
        float v = p[m][j];
        v += __shfl_xor(v, 1);
        v += __shfl_xor(v, 2);
        v += __shfl_xor(v, 4);
        v += __shfl_xor(v, 8);
        p[m][j] = v;               // valid at lanes with (lane&15)==0
      }
    int rl = wr * 64 + (lane >> 4) * 4;
    if (wc == 0 && (lane & 15) == 0) {
      #pragma unroll
      for (int m = 0; m < 4; m++)
        #pragma unroll
        for (int j = 0; j < 4; j++) lRed[rl + m * 16 + j] = p[m][j];
    }
    __syncthreads();
    if (wc == 1 && (lane & 15) == 0) {
      #pragma unroll
      for (int m = 0; m < 4; m++)
        #pragma unroll
        for (int j = 0; j < 4; j++)
          atomicAdd(&s2out[m0 + rl + m * 16 + j], lRed[rl + m * 16 + j] + p[m][j]);
    }
  }
}

// ---------- wide transpose: out[c][r] = in[r][c] * (SCALE ? v[r] : 1) ----------
template <int SCALE>
__global__ __launch_bounds__(256) void wide_transpose_kernel(
    const bf16_t* __restrict__ in, bf16_t* __restrict__ out,
    const float* __restrict__ vscale, int inRows, int inCols) {
  __shared__ bf16_t tl[32][66];
  size_t base = (size_t)blockIdx.z * inRows * inCols;
  int r0 = blockIdx.y * 32, c0 = blockIdx.x * 64;
  int row = threadIdx.x >> 3, cc8 = (threadIdx.x & 7) * 8;
  *(bf16x8*)&tl[row][cc8] =
      *(const bf16x8*)(in + base + (size_t)(r0 + row) * inCols + c0 + cc8);
  __syncthreads();
  int orow = threadIdx.x >> 2;
  int rq = (threadIdx.x & 3) * 8;
  bf16x8 o;
  if (SCALE) {
    const float* vp = vscale + (size_t)blockIdx.z * inRows + r0 + rq;
    float4 va = *(const float4*)vp;
    float4 vb = *(const float4*)(vp + 4);
    o[0] = (__bf16)((float)tl[rq + 0][orow] * va.x);
    o[1] = (__bf16)((float)tl[rq + 1][orow] * va.y);
    o[2] = (__bf16)((float)tl[rq + 2][orow] * va.z);
    o[3] = (__bf16)((float)tl[rq + 3][orow] * va.w);
    o[4] = (__bf16)((float)tl[rq + 4][orow] * vb.x);
    o[5] = (__bf16)((float)tl[rq + 5][orow] * vb.y);
    o[6] = (__bf16)((float)tl[rq + 6][orow] * vb.z);
    o[7] = (__bf16)((float)tl[rq + 7][orow] * vb.w);
  } else {
    #pragma unroll
    for (int i = 0; i < 8; i++) o[i] = tl[rq + i][orow];
  }
  *(bf16x8*)(out + base + (size_t)(c0 + orow) * inRows + r0 + rq) = o;
}

// ---------- Sinkhorn half-iteration, grid-wide ----------
template <int INIT>
__global__ __launch_bounds__(256) void sink_pass_kernel(
    const bf16_t* __restrict__ Mmat, const float* __restrict__ x,
    const float* __restrict__ w, float* __restrict__ y) {
  const int b = blockIdx.y;
  const int t = threadIdx.x;
  __shared__ float xs[512];
  if (!INIT) {
    ((float2*)xs)[t] = ((const float2*)(x + b * 512))[t];
    __syncthreads();
  }
  const int row = blockIdx.x * 64 + (t >> 2);
  const int seg = t & 3;
  const bf16_t* rp = Mmat + ((size_t)b * 512 + row) * 512;
  float sum = 0.f;
  #pragma unroll
  for (int j = 0; j < 16; j++) {
    bf16x8 kv = *(const bf16x8*)(rp + seg * 8 + j * 32);
    if (INIT) {
      sum += (float)kv[0] + (float)kv[1] + (float)kv[2] + (float)kv[3] +
             (float)kv[4] + (float)kv[5] + (float)kv[6] + (float)kv[7];
    } else {
      const float4* xp = (const float4*)&xs[seg * 8 + j * 32];
      float4 x0 = xp[0], x1 = xp[1];
      sum += (float)kv[0] * x0.x + (float)kv[1] * x0.y + (float)kv[2] * x0.z +
             (float)kv[3] * x0.w + (float)kv[4] * x1.x + (float)kv[5] * x1.y +
             (float)kv[6] * x1.z + (float)kv[7] * x1.w;
    }
  }
  if (INIT) sum *= (1.0f / 512.0f);
  sum += __shfl_xor(sum, 1);
  sum += __shfl_xor(sum, 2);
  if (seg == 0)
    y[b * 512 + row] = powf(w[b * 512 + row] / sum, 10.0f / 10.1f);
}

// ---------- Sinkhorn closed-form extrapolation to iteration 100 ----------
// args: (prev u, curr u, prev v, curr v); x_100 = x_M * exp(rho_M * G)
__global__ __launch_bounds__(512) void sink_final_kernel(
    const float* __restrict__ ua, const float* __restrict__ ub,
    const float* __restrict__ va, const float* __restrict__ vb,
    float* __restrict__ u_out, float* __restrict__ v_out, float Gf) {
  const int b = blockIdx.x, t = threadIdx.x, idx = b * 512 + t;
  const float ubv = ub[idx], vbv = vb[idx];
  float su = logf(ubv / ua[idx]);
  float sv = logf(vbv / va[idx]);
  #pragma unroll
  for (int ofs = 32; ofs > 0; ofs >>= 1) {
    su += __shfl_down(su, ofs);
    sv += __shfl_down(sv, ofs);
  }
  __shared__ float r0[8], r1[8];
  __shared__ float mu, mv;
  if ((t & 63) == 0) { r0[t >> 6] = su; r1[t >> 6] = sv; }
  __syncthreads();
  if (t == 0) {
    float a = 0.f, c = 0.f;
    #pragma unroll
    for (int i = 0; i < 8; i++) { a += r0[i]; c += r1[i]; }
    mu = a / 512.f; mv = c / 512.f;
  }
  __syncthreads();
  u_out[idx] = ubv * expf(Gf * mu);
  v_out[idx] = vbv * expf(Gf * mv);
}

extern "C" void kernel_launch(void* const* d_in, const int* in_sizes, int n_in,
                              void* d_out, int out_size, void* d_ws, size_t ws_size,
                              hipStream_t stream) {
  (void)in_sizes; (void)n_in; (void)out_size; (void)ws_size;
  const float* src = (const float*)d_in[0];   // [32,512,1024]
  const float* tgt = (const float*)d_in[1];   // [32,512,1024]
  const int* smask = (const int*)d_in[2];     // [32,512]
  const int* gmask = (const int*)d_in[3];     // [32,512]
  const float* W   = (const float*)d_in[4];   // [1024,1024]
  const float* bias = (const float*)d_in[5];  // [1024]
  float* out = (float*)d_out;                 // [32,512,1024]

  uint8_t* ws = (uint8_t*)d_ws;
  bf16_t* s_bf  = (bf16_t*)(ws + 0);          // 32 MB
  bf16_t* Kmat  = (bf16_t*)(ws + 0);          // reuse after gemm1: 16 MB
  bf16_t* KTmat = (bf16_t*)(ws + 16777216);   // 16 MB
  bf16_t* W_bf  = (bf16_t*)(ws + 33554432);   // 2 MB
  float* ua = (float*)(ws + 33554432);        // overwrite W_bf after gemm1
  float* ub = ua + 16384;
  float* va = ub + 16384;
  float* vb = va + 16384;
  bf16_t* g_bf  = (bf16_t*)(ws + 35651584);   // 32 MB
  bf16_t* t_bf  = (bf16_t*)(ws + 69206016);   // 32 MB
  bf16_t* gTv   = (bf16_t*)(ws + 69206016);   // reuse after gemm2
  float* s2  = (float*)(ws + 102760448);
  float* g2  = s2 + 16384;
  float* swv = g2 + 16384;
  float* gwv = swv + 16384;
  float* uv  = gwv + 16384;
  float* vv  = uv + 16384;

  // 1. conversions + g norms; zero s2 for fused-norm atomics
  cvt2_kernel<<<8704, 256, 0, stream>>>(src, s_bf, 2097152, W, W_bf);
  prep_g_kernel<<<16384, 128, 0, stream>>>(tgt, g_bf, g2);
  hipMemsetAsync(s2, 0, 16384 * sizeof(float), stream);

  // 2. t = s @ W^T + b  (M=16384,N=1024,K=1024) + fused row norms -> s2
  gemm_bt_kernel<0, 8, 128><<<1024, 256, 0, stream>>>(
      s_bf, W_bf, 1024, 0, 0, t_bf, 0, 1024, bias,
      nullptr, nullptr, nullptr, nullptr, nullptr, s2);

  // 3. weights (both sides, one dispatch)
  weights2_kernel<<<64, 512, 0, stream>>>(s2, smask, swv, g2, gmask, gwv);

  // 4. K = exp(-10*cost)  (per batch 512x512, K=1024)
  gemm_bt_kernel<1, 4, 4><<<512, 256, 0, stream>>>(
      t_bf, g_bf, 1024, (size_t)512 * 1024, (size_t)512 * 1024,
      Kmat, (size_t)512 * 512, 512, nullptr, s2, g2, swv, gwv, nullptr, nullptr);

  // 5. K^T (wide transpose)
  wide_transpose_kernel<0><<<dim3(8, 16, 32), 256, 0, stream>>>(
      Kmat, KTmat, nullptr, NS, NG);

  // 6. Sinkhorn: 3 real iterations (6 passes) + extrapolation.
  // u1->ua v1->va u2->ub v2->vb u3->ua v3->va; ratios (prev=ub,curr=ua) etc.
  dim3 pg(NS / 64, NBATCH);
  sink_pass_kernel<1><<<pg, 256, 0, stream>>>(Kmat, nullptr, swv, ua);   // u1
  sink_pass_kernel<0><<<pg, 256, 0, stream>>>(KTmat, ua, gwv, va);       // v1
  sink_pass_kernel<0><<<pg, 256, 0, stream>>>(Kmat, va, swv, ub);        // u2
  sink_pass_kernel<0><<<pg, 256, 0, stream>>>(KTmat, ub, gwv, vb);       // v2
  sink_pass_kernel<0><<<pg, 256, 0, stream>>>(Kmat, vb, swv, ua);        // u3
  sink_pass_kernel<0><<<pg, 256, 0, stream>>>(KTmat, ua, gwv, va);       // v3

  // G = sum_{j=1}^{100-M_REAL} fi^(2j) in double
  double fi2 = (10.0 / 10.1) * (10.0 / 10.1);
  double Gd = 0.0, pd = 1.0;
  for (int j = 0; j < (N_TOT - M_REAL); j++) { pd *= fi2; Gd += pd; }
  sink_final_kernel<<<32, 512, 0, stream>>>(ub, ua, vb, va, uv, vv, (float)Gd);

  // 7. gTv[h][g] = v[g]*g[g][h] (wide transpose + scale)
  wide_transpose_kernel<1><<<dim3(16, 16, 32), 256, 0, stream>>>(
      g_bf, gTv, vv, NG, NH);

  // 8. aligned = u .* (K @ gTv)  (per batch 512x1024, K=512)
  gemm_bt_kernel<2, 8, 4><<<1024, 256, 0, stream>>>(
      Kmat, gTv, 512, (size_t)512 * 512, (size_t)1024 * 512,
      out, (size_t)512 * 1024, 1024, nullptr, nullptr, nullptr, nullptr, nullptr, uv, nullptr);
}

// Round 10
// 192.201 us; speedup vs baseline: 1.3030x; 1.1682x over previous
//
#include <hip/hip_runtime.h>
#include <hip/hip_bf16.h>
#include <math.h>

// EmbeddingAlignerOT on MI355X.
// R10: GEMM K-loop restructured to double-buffered stage-at-top with COUNTED
// vmcnt (T3-lite/T4): issue next K-step's global_load_lds into buf^1, then
// s_waitcnt vmcnt(4) (waits only the CURRENT step's loads, issued one full
// iteration ago; next step's 4 loads stay in flight across the barrier),
// raw s_barrier, compute, closing barrier. Race-safety: buf^1 overwrite is
// issued only after the closing barrier ending all reads of it; vmcnt+barrier
// precede all reads of buf. M_REAL=2 (4 sink passes). Rest as R9.
// Workspace (~103.2 MB): [0,32M) s_bf -> K+KT after gemm1 | [32M,34M) W_bf ->
// ua/ub/va/vb | [34M,66M) g_bf | [66M,98M) t_bf -> gTv | [98M..) scalars.

typedef __bf16 bf16_t;
typedef __bf16 bf16x8 __attribute__((ext_vector_type(8)));
typedef float  f32x4  __attribute__((ext_vector_type(4)));

#define NBATCH 32
#define NS 512
#define NG 512
#define NH 1024
#define M_REAL 2
#define N_TOT 100

__device__ __forceinline__ void async_copy16(const void* gsrc, void* ldst) {
  __builtin_amdgcn_global_load_lds(
      (__attribute__((address_space(1))) void*)gsrc,
      (__attribute__((address_space(3))) void*)ldst, 16, 0, 0);
}

// ---------- fp32 -> bf16 convert, src and W in one dispatch ----------
__global__ __launch_bounds__(256) void cvt2_kernel(const float* __restrict__ a,
                                                   bf16_t* __restrict__ outa, int n8a,
                                                   const float* __restrict__ b,
                                                   bf16_t* __restrict__ outb) {
  int i = blockIdx.x * 256 + threadIdx.x;
  const float* src;
  bf16_t* dst;
  int idx;
  if (i < n8a) { src = a; dst = outa; idx = i; }
  else         { src = b; dst = outb; idx = i - n8a; }
  const float4* p = (const float4*)src + (size_t)idx * 2;
  float4 x = p[0], y = p[1];
  bf16x8 o;
  o[0] = (__bf16)x.x; o[1] = (__bf16)x.y; o[2] = (__bf16)x.z; o[3] = (__bf16)x.w;
  o[4] = (__bf16)y.x; o[5] = (__bf16)y.y; o[6] = (__bf16)y.z; o[7] = (__bf16)y.w;
  ((bf16x8*)dst)[idx] = o;
}

// ---------- target: convert to bf16 + fp32 row norms ----------
__global__ __launch_bounds__(128) void prep_g_kernel(const float* __restrict__ g,
                                                     bf16_t* __restrict__ gb,
                                                     float* __restrict__ g2) {
  int row = blockIdx.x;   // B*G rows of length NH
  int t = threadIdx.x;    // 128
  const float* rp = g + (size_t)row * NH + t * 8;
  float4 a = *(const float4*)rp;
  float4 b = *(const float4*)(rp + 4);
  bf16x8 o;
  o[0] = (__bf16)a.x; o[1] = (__bf16)a.y; o[2] = (__bf16)a.z; o[3] = (__bf16)a.w;
  o[4] = (__bf16)b.x; o[5] = (__bf16)b.y; o[6] = (__bf16)b.z; o[7] = (__bf16)b.w;
  ((bf16x8*)(gb + (size_t)row * NH))[t] = o;
  float ss = a.x*a.x + a.y*a.y + a.z*a.z + a.w*a.w
           + b.x*b.x + b.y*b.y + b.z*b.z + b.w*b.w;
  #pragma unroll
  for (int ofs = 32; ofs > 0; ofs >>= 1) ss += __shfl_down(ss, ofs);
  __shared__ float wsum[2];
  if ((t & 63) == 0) wsum[t >> 6] = ss;
  __syncthreads();
  if (t == 0) g2[row] = wsum[0] + wsum[1];
}

// ---------- adjusted weights for BOTH sides in one dispatch ----------
__global__ __launch_bounds__(512) void weights2_kernel(
    const float* __restrict__ s2, const int* __restrict__ smask, float* __restrict__ swv,
    const float* __restrict__ g2, const int* __restrict__ gmask, float* __restrict__ gwv) {
  int which = blockIdx.x >> 5;
  int bb = blockIdx.x & 31, t = threadIdx.x;
  const float* n2 = which ? g2 : s2;
  const int* mask = which ? gmask : smask;
  float* wout = which ? gwv : swv;
  int idx = bb * 512 + t;
  float mag = sqrtf(n2[idx]) + 1e-12f;
  float w = (float)mask[idx] * mag + 1e-12f;
  float ss = w;
  #pragma unroll
  for (int ofs = 32; ofs > 0; ofs >>= 1) ss += __shfl_down(ss, ofs);
  __shared__ float red[8];
  __shared__ float tot;
  if ((t & 63) == 0) red[t >> 6] = ss;
  __syncthreads();
  if (t == 0) {
    float x = 0.f;
    #pragma unroll
    for (int i = 0; i < 8; i++) x += red[i];
    tot = fmaxf(x, 1e-12f);
  }
  __syncthreads();
  wout[idx] = w / tot;
}

// ---------- C = A * B^T, 128x128 tile, BK=32, 4 waves, bf16 MFMA ----------
// Double-buffered K-loop, stage-at-top, counted vmcnt(4), raw barriers.
// XCD-aware bijective swizzle (1-D grid, nwg%8==0).
// MODE 0: t = A@B^T + bias, bf16 store; fused row-norm atomicAdd into s2out
// MODE 1: K = exp(-10*(sqrt(s2+g2-2C)*sw*gw+eps)) bf16 store (batched)
// MODE 2: out = u .* C, fp32 store (batched)
template <int MODE, int GX, int GY>
__global__ __launch_bounds__(256) void gemm_bt_kernel(
    const bf16_t* __restrict__ A, const bf16_t* __restrict__ Bm, int K_len,
    size_t strideAb, size_t strideBb,
    void* __restrict__ outp, size_t strideOb, int ldc,
    const float* __restrict__ bias,
    const float* __restrict__ s2, const float* __restrict__ g2,
    const float* __restrict__ sw, const float* __restrict__ gw,
    const float* __restrict__ uvec, float* __restrict__ s2out) {
  __shared__ bf16_t lds[2][2][128 * 32];   // [buf][A=0/B=1][row*32+col]
  const int nwg = gridDim.x;
  const int lin = blockIdx.x;
  const int lin2 = (lin & 7) * (nwg >> 3) + (lin >> 3);
  const int bx = lin2 % GX;
  const int by = (lin2 / GX) % GY;
  const int bz = lin2 / (GX * GY);
  const int tid = threadIdx.x, lane = tid & 63, wave = tid >> 6;
  const int wr = wave >> 1, wc = wave & 1;
  const bf16_t* Ab = A + (size_t)bz * strideAb;
  const bf16_t* Bb = Bm + (size_t)bz * strideBb;
  const int m0 = by * 128, n0 = bx * 128;
  const int rA = lane >> 2;       // row within 16-row staging group
  const int c8 = (lane & 3) * 8;  // bf16 col offset of this lane's 16B chunk

  // stage one 128x32 A-tile + B-tile into lds[buf] (4 gloads per wave)
  auto stage = [&](int kt, int buf) {
    #pragma unroll
    for (int c = 0; c < 2; c++) {
      int rg = (c * 4 + wave) * 16;
      async_copy16(Ab + (size_t)(m0 + rg + rA) * K_len + kt + c8, &lds[buf][0][rg * 32]);
      async_copy16(Bb + (size_t)(n0 + rg + rA) * K_len + kt + c8, &lds[buf][1][rg * 32]);
    }
  };

  f32x4 acc[4][4];
  #pragma unroll
  for (int i = 0; i < 4; i++)
    #pragma unroll
    for (int j = 0; j < 4; j++) { f32x4 z = {0.f, 0.f, 0.f, 0.f}; acc[i][j] = z; }

  stage(0, 0);
  int bufsel = 0;
  for (int kt = 0; kt < K_len; kt += 32) {
    if (kt + 32 < K_len) {
      stage(kt + 32, bufsel ^ 1);                      // next step into other buf
      asm volatile("s_waitcnt vmcnt(4)" ::: "memory"); // wait ONLY current step
    } else {
      asm volatile("s_waitcnt vmcnt(0)" ::: "memory"); // last step: full wait
    }
    __builtin_amdgcn_s_barrier();   // all waves: data ready, prev reads done
    bf16x8 af[4], bf[4];
    #pragma unroll
    for (int m = 0; m < 4; m++)
      af[m] = *(const bf16x8*)&lds[bufsel][0][(wr * 64 + m * 16 + (lane & 15)) * 32 + (lane >> 4) * 8];
    #pragma unroll
    for (int n = 0; n < 4; n++)
      bf[n] = *(const bf16x8*)&lds[bufsel][1][(wc * 64 + n * 16 + (lane & 15)) * 32 + (lane >> 4) * 8];
    #pragma unroll
    for (int m = 0; m < 4; m++)
      #pragma unroll
      for (int n = 0; n < 4; n++)
        acc[m][n] = __builtin_amdgcn_mfma_f32_16x16x32_bf16(af[m], bf[n], acc[m][n], 0, 0, 0);
    __builtin_amdgcn_s_barrier();   // reads of lds[bufsel] complete
    bufsel ^= 1;
  }

  // epilogue: C/D frag mapping col=lane&15, row=(lane>>4)*4+j
  const int bo = bz * 512;
  const int row_base = m0 + wr * 64, col_base = n0 + wc * 64;
  const int r_off = (lane >> 4) * 4, c_off = lane & 15;
  float p[4][4];   // MODE0: per-thread row partial sums of (val+bias)^2
  #pragma unroll
  for (int m = 0; m < 4; m++)
    #pragma unroll
    for (int j = 0; j < 4; j++) p[m][j] = 0.f;

  #pragma unroll
  for (int m = 0; m < 4; m++) {
    #pragma unroll
    for (int n = 0; n < 4; n++) {
      #pragma unroll
      for (int j = 0; j < 4; j++) {
        int gm = row_base + m * 16 + r_off + j;
        int gn = col_base + n * 16 + c_off;
        float val = acc[m][n][j];
        if (MODE == 0) {
          float tv = val + bias[gn];
          ((bf16_t*)outp)[(size_t)gm * ldc + gn] = (__bf16)tv;
          p[m][j] += tv * tv;
        } else if (MODE == 1) {
          float sq = s2[bo + gm] + g2[bo + gn] - 2.0f * val;
          float d = sqrtf(fmaxf(sq, 0.0f));
          float cost = d * sw[bo + gm] * gw[bo + gn] + 1e-12f;
          ((bf16_t*)outp + (size_t)bz * strideOb)[(size_t)gm * ldc + gn] =
              (__bf16)expf(-10.0f * cost);
        } else {
          ((float*)outp + (size_t)bz * strideOb)[(size_t)gm * ldc + gn] =
              uvec[bo + gm] * val;
        }
      }
    }
  }

  if (MODE == 0) {
    // reduce (val+bias)^2 across the 128 cols this block owns -> atomicAdd s2out
    __syncthreads();                    // all LDS reads done; reuse lds
    float* lRed = (float*)&lds[0][0][0];  // 128 floats
    #pragma unroll
    for (int m = 0; m < 4; m++)
      #pragma unroll
      for (int j = 0; j < 4; j++) {
        float v = p[m][j];
        v += __shfl_xor(v, 1);
        v += __shfl_xor(v, 2);
        v += __shfl_xor(v, 4);
        v += __shfl_xor(v, 8);
        p[m][j] = v;               // valid at lanes with (lane&15)==0
      }
    int rl = wr * 64 + (lane >> 4) * 4;
    if (wc == 0 && (lane & 15) == 0) {
      #pragma unroll
      for (int m = 0; m < 4; m++)
        #pragma unroll
        for (int j = 0; j < 4; j++) lRed[rl + m * 16 + j] = p[m][j];
    }
    __syncthreads();
    if (wc == 1 && (lane & 15) == 0) {
      #pragma unroll
      for (int m = 0; m < 4; m++)
        #pragma unroll
        for (int j = 0; j < 4; j++)
          atomicAdd(&s2out[m0 + rl + m * 16 + j], lRed[rl + m * 16 + j] + p[m][j]);
    }
  }
}

// ---------- wide transpose: out[c][r] = in[r][c] * (SCALE ? v[r] : 1) ----------
template <int SCALE>
__global__ __launch_bounds__(256) void wide_transpose_kernel(
    const bf16_t* __restrict__ in, bf16_t* __restrict__ out,
    const float* __restrict__ vscale, int inRows, int inCols) {
  __shared__ bf16_t tl[32][66];
  size_t base = (size_t)blockIdx.z * inRows * inCols;
  int r0 = blockIdx.y * 32, c0 = blockIdx.x * 64;
  int row = threadIdx.x >> 3, cc8 = (threadIdx.x & 7) * 8;
  *(bf16x8*)&tl[row][cc8] =
      *(const bf16x8*)(in + base + (size_t)(r0 + row) * inCols + c0 + cc8);
  __syncthreads();
  int orow = threadIdx.x >> 2;
  int rq = (threadIdx.x & 3) * 8;
  bf16x8 o;
  if (SCALE) {
    const float* vp = vscale + (size_t)blockIdx.z * inRows + r0 + rq;
    float4 va = *(const float4*)vp;
    float4 vb = *(const float4*)(vp + 4);
    o[0] = (__bf16)((float)tl[rq + 0][orow] * va.x);
    o[1] = (__bf16)((float)tl[rq + 1][orow] * va.y);
    o[2] = (__bf16)((float)tl[rq + 2][orow] * va.z);
    o[3] = (__bf16)((float)tl[rq + 3][orow] * va.w);
    o[4] = (__bf16)((float)tl[rq + 4][orow] * vb.x);
    o[5] = (__bf16)((float)tl[rq + 5][orow] * vb.y);
    o[6] = (__bf16)((float)tl[rq + 6][orow] * vb.z);
    o[7] = (__bf16)((float)tl[rq + 7][orow] * vb.w);
  } else {
    #pragma unroll
    for (int i = 0; i < 8; i++) o[i] = tl[rq + i][orow];
  }
  *(bf16x8*)(out + base + (size_t)(c0 + orow) * inRows + r0 + rq) = o;
}

// ---------- Sinkhorn half-iteration, grid-wide ----------
template <int INIT>
__global__ __launch_bounds__(256) void sink_pass_kernel(
    const bf16_t* __restrict__ Mmat, const float* __restrict__ x,
    const float* __restrict__ w, float* __restrict__ y) {
  const int b = blockIdx.y;
  const int t = threadIdx.x;
  __shared__ float xs[512];
  if (!INIT) {
    ((float2*)xs)[t] = ((const float2*)(x + b * 512))[t];
    __syncthreads();
  }
  const int row = blockIdx.x * 64 + (t >> 2);
  const int seg = t & 3;
  const bf16_t* rp = Mmat + ((size_t)b * 512 + row) * 512;
  float sum = 0.f;
  #pragma unroll
  for (int j = 0; j < 16; j++) {
    bf16x8 kv = *(const bf16x8*)(rp + seg * 8 + j * 32);
    if (INIT) {
      sum += (float)kv[0] + (float)kv[1] + (float)kv[2] + (float)kv[3] +
             (float)kv[4] + (float)kv[5] + (float)kv[6] + (float)kv[7];
    } else {
      const float4* xp = (const float4*)&xs[seg * 8 + j * 32];
      float4 x0 = xp[0], x1 = xp[1];
      sum += (float)kv[0] * x0.x + (float)kv[1] * x0.y + (float)kv[2] * x0.z +
             (float)kv[3] * x0.w + (float)kv[4] * x1.x + (float)kv[5] * x1.y +
             (float)kv[6] * x1.z + (float)kv[7] * x1.w;
    }
  }
  if (INIT) sum *= (1.0f / 512.0f);
  sum += __shfl_xor(sum, 1);
  sum += __shfl_xor(sum, 2);
  if (seg == 0)
    y[b * 512 + row] = powf(w[b * 512 + row] / sum, 10.0f / 10.1f);
}

// ---------- Sinkhorn closed-form extrapolation to iteration 100 ----------
// args: (prev u, curr u, prev v, curr v); x_100 = x_M * exp(rho_M * G)
__global__ __launch_bounds__(512) void sink_final_kernel(
    const float* __restrict__ ua, const float* __restrict__ ub,
    const float* __restrict__ va, const float* __restrict__ vb,
    float* __restrict__ u_out, float* __restrict__ v_out, float Gf) {
  const int b = blockIdx.x, t = threadIdx.x, idx = b * 512 + t;
  const float ubv = ub[idx], vbv = vb[idx];
  float su = logf(ubv / ua[idx]);
  float sv = logf(vbv / va[idx]);
  #pragma unroll
  for (int ofs = 32; ofs > 0; ofs >>= 1) {
    su += __shfl_down(su, ofs);
    sv += __shfl_down(sv, ofs);
  }
  __shared__ float r0[8], r1[8];
  __shared__ float mu, mv;
  if ((t & 63) == 0) { r0[t >> 6] = su; r1[t >> 6] = sv; }
  __syncthreads();
  if (t == 0) {
    float a = 0.f, c = 0.f;
    #pragma unroll
    for (int i = 0; i < 8; i++) { a += r0[i]; c += r1[i]; }
    mu = a / 512.f; mv = c / 512.f;
  }
  __syncthreads();
  u_out[idx] = ubv * expf(Gf * mu);
  v_out[idx] = vbv * expf(Gf * mv);
}

extern "C" void kernel_launch(void* const* d_in, const int* in_sizes, int n_in,
                              void* d_out, int out_size, void* d_ws, size_t ws_size,
                              hipStream_t stream) {
  (void)in_sizes; (void)n_in; (void)out_size; (void)ws_size;
  const float* src = (const float*)d_in[0];   // [32,512,1024]
  const float* tgt = (const float*)d_in[1];   // [32,512,1024]
  const int* smask = (const int*)d_in[2];     // [32,512]
  const int* gmask = (const int*)d_in[3];     // [32,512]
  const float* W   = (const float*)d_in[4];   // [1024,1024]
  const float* bias = (const float*)d_in[5];  // [1024]
  float* out = (float*)d_out;                 // [32,512,1024]

  uint8_t* ws = (uint8_t*)d_ws;
  bf16_t* s_bf  = (bf16_t*)(ws + 0);          // 32 MB
  bf16_t* Kmat  = (bf16_t*)(ws + 0);          // reuse after gemm1: 16 MB
  bf16_t* KTmat = (bf16_t*)(ws + 16777216);   // 16 MB
  bf16_t* W_bf  = (bf16_t*)(ws + 33554432);   // 2 MB
  float* ua = (float*)(ws + 33554432);        // overwrite W_bf after gemm1
  float* ub = ua + 16384;
  float* va = ub + 16384;
  float* vb = va + 16384;
  bf16_t* g_bf  = (bf16_t*)(ws + 35651584);   // 32 MB
  bf16_t* t_bf  = (bf16_t*)(ws + 69206016);   // 32 MB
  bf16_t* gTv   = (bf16_t*)(ws + 69206016);   // reuse after gemm2
  float* s2  = (float*)(ws + 102760448);
  float* g2  = s2 + 16384;
  float* swv = g2 + 16384;
  float* gwv = swv + 16384;
  float* uv  = gwv + 16384;
  float* vv  = uv + 16384;

  // 1. conversions + g norms; zero s2 for fused-norm atomics
  cvt2_kernel<<<8704, 256, 0, stream>>>(src, s_bf, 2097152, W, W_bf);
  prep_g_kernel<<<16384, 128, 0, stream>>>(tgt, g_bf, g2);
  hipMemsetAsync(s2, 0, 16384 * sizeof(float), stream);

  // 2. t = s @ W^T + b  (M=16384,N=1024,K=1024) + fused row norms -> s2
  gemm_bt_kernel<0, 8, 128><<<1024, 256, 0, stream>>>(
      s_bf, W_bf, 1024, 0, 0, t_bf, 0, 1024, bias,
      nullptr, nullptr, nullptr, nullptr, nullptr, s2);

  // 3. weights (both sides, one dispatch)
  weights2_kernel<<<64, 512, 0, stream>>>(s2, smask, swv, g2, gmask, gwv);

  // 4. K = exp(-10*cost)  (per batch 512x512, K=1024)
  gemm_bt_kernel<1, 4, 4><<<512, 256, 0, stream>>>(
      t_bf, g_bf, 1024, (size_t)512 * 1024, (size_t)512 * 1024,
      Kmat, (size_t)512 * 512, 512, nullptr, s2, g2, swv, gwv, nullptr, nullptr);

  // 5. K^T (wide transpose)
  wide_transpose_kernel<0><<<dim3(8, 16, 32), 256, 0, stream>>>(
      Kmat, KTmat, nullptr, NS, NG);

  // 6. Sinkhorn: 2 real iterations (4 passes) + extrapolation.
  // u1->ua v1->va u2->ub v2->vb; ratios (prev=ua,curr=ub),(va,vb).
  dim3 pg(NS / 64, NBATCH);
  sink_pass_kernel<1><<<pg, 256, 0, stream>>>(Kmat, nullptr, swv, ua);   // u1
  sink_pass_kernel<0><<<pg, 256, 0, stream>>>(KTmat, ua, gwv, va);       // v1
  sink_pass_kernel<0><<<pg, 256, 0, stream>>>(Kmat, va, swv, ub);        // u2
  sink_pass_kernel<0><<<pg, 256, 0, stream>>>(KTmat, ub, gwv, vb);       // v2

  // G = sum_{j=1}^{100-M_REAL} fi^(2j) in double
  double fi2 = (10.0 / 10.1) * (10.0 / 10.1);
  double Gd = 0.0, pd = 1.0;
  for (int j = 0; j < (N_TOT - M_REAL); j++) { pd *= fi2; Gd += pd; }
  sink_final_kernel<<<32, 512, 0, stream>>>(ua, ub, va, vb, uv, vv, (float)Gd);

  // 7. gTv[h][g] = v[g]*g[g][h] (wide transpose + scale)
  wide_transpose_kernel<1><<<dim3(16, 16, 32), 256, 0, stream>>>(
      g_bf, gTv, vv, NG, NH);

  // 8. aligned = u .* (K @ gTv)  (per batch 512x1024, K=512)
  gemm_bt_kernel<2, 8, 4><<<1024, 256, 0, stream>>>(
      Kmat, gTv, 512, (size_t)512 * 512, (size_t)1024 * 512,
      out, (size_t)512 * 1024, 1024, nullptr, nullptr, nullptr, nullptr, nullptr, uv, nullptr);
}

// Round 11
// 191.863 us; speedup vs baseline: 1.3053x; 1.0018x over previous
//
#include <hip/hip_runtime.h>
#include <hip/hip_bf16.h>
#include <math.h>

// EmbeddingAlignerOT on MI355X.
// R11: chunk-XOR LDS swizzle (T2) on all GEMM tiles. LDS dest stays linear
// (global_load_lds requirement); the per-lane GLOBAL source chunk is
// pre-swizzled (ch ^ row&3 within each 64B row), and ds_read applies the
// same involution. Each 32-lane half then hits all 8 bank groups (4
// lanes/group, optimal) instead of 4 groups at 8 lanes. Rest as R10
// (counted-vmcnt dbuf K-loop, fused norms, M_REAL=2, wide transposes).
// Workspace (~103.2 MB): [0,32M) s_bf -> K+KT after gemm1 | [32M,34M) W_bf ->
// ua/ub/va/vb | [34M,66M) g_bf | [66M,98M) t_bf -> gTv | [98M..) scalars.

typedef __bf16 bf16_t;
typedef __bf16 bf16x8 __attribute__((ext_vector_type(8)));
typedef float  f32x4  __attribute__((ext_vector_type(4)));

#define NBATCH 32
#define NS 512
#define NG 512
#define NH 1024
#define M_REAL 2
#define N_TOT 100

__device__ __forceinline__ void async_copy16(const void* gsrc, void* ldst) {
  __builtin_amdgcn_global_load_lds(
      (__attribute__((address_space(1))) void*)gsrc,
      (__attribute__((address_space(3))) void*)ldst, 16, 0, 0);
}

// ---------- fp32 -> bf16 convert, src and W in one dispatch ----------
__global__ __launch_bounds__(256) void cvt2_kernel(const float* __restrict__ a,
                                                   bf16_t* __restrict__ outa, int n8a,
                                                   const float* __restrict__ b,
                                                   bf16_t* __restrict__ outb) {
  int i = blockIdx.x * 256 + threadIdx.x;
  const float* src;
  bf16_t* dst;
  int idx;
  if (i < n8a) { src = a; dst = outa; idx = i; }
  else         { src = b; dst = outb; idx = i - n8a; }
  const float4* p = (const float4*)src + (size_t)idx * 2;
  float4 x = p[0], y = p[1];
  bf16x8 o;
  o[0] = (__bf16)x.x; o[1] = (__bf16)x.y; o[2] = (__bf16)x.z; o[3] = (__bf16)x.w;
  o[4] = (__bf16)y.x; o[5] = (__bf16)y.y; o[6] = (__bf16)y.z; o[7] = (__bf16)y.w;
  ((bf16x8*)dst)[idx] = o;
}

// ---------- target: convert to bf16 + fp32 row norms ----------
__global__ __launch_bounds__(128) void prep_g_kernel(const float* __restrict__ g,
                                                     bf16_t* __restrict__ gb,
                                                     float* __restrict__ g2) {
  int row = blockIdx.x;   // B*G rows of length NH
  int t = threadIdx.x;    // 128
  const float* rp = g + (size_t)row * NH + t * 8;
  float4 a = *(const float4*)rp;
  float4 b = *(const float4*)(rp + 4);
  bf16x8 o;
  o[0] = (__bf16)a.x; o[1] = (__bf16)a.y; o[2] = (__bf16)a.z; o[3] = (__bf16)a.w;
  o[4] = (__bf16)b.x; o[5] = (__bf16)b.y; o[6] = (__bf16)b.z; o[7] = (__bf16)b.w;
  ((bf16x8*)(gb + (size_t)row * NH))[t] = o;
  float ss = a.x*a.x + a.y*a.y + a.z*a.z + a.w*a.w
           + b.x*b.x + b.y*b.y + b.z*b.z + b.w*b.w;
  #pragma unroll
  for (int ofs = 32; ofs > 0; ofs >>= 1) ss += __shfl_down(ss, ofs);
  __shared__ float wsum[2];
  if ((t & 63) == 0) wsum[t >> 6] = ss;
  __syncthreads();
  if (t == 0) g2[row] = wsum[0] + wsum[1];
}

// ---------- adjusted weights for BOTH sides in one dispatch ----------
__global__ __launch_bounds__(512) void weights2_kernel(
    const float* __restrict__ s2, const int* __restrict__ smask, float* __restrict__ swv,
    const float* __restrict__ g2, const int* __restrict__ gmask, float* __restrict__ gwv) {
  int which = blockIdx.x >> 5;
  int bb = blockIdx.x & 31, t = threadIdx.x;
  const float* n2 = which ? g2 : s2;
  const int* mask = which ? gmask : smask;
  float* wout = which ? gwv : swv;
  int idx = bb * 512 + t;
  float mag = sqrtf(n2[idx]) + 1e-12f;
  float w = (float)mask[idx] * mag + 1e-12f;
  float ss = w;
  #pragma unroll
  for (int ofs = 32; ofs > 0; ofs >>= 1) ss += __shfl_down(ss, ofs);
  __shared__ float red[8];
  __shared__ float tot;
  if ((t & 63) == 0) red[t >> 6] = ss;
  __syncthreads();
  if (t == 0) {
    float x = 0.f;
    #pragma unroll
    for (int i = 0; i < 8; i++) x += red[i];
    tot = fmaxf(x, 1e-12f);
  }
  __syncthreads();
  wout[idx] = w / tot;
}

// ---------- C = A * B^T, 128x128 tile, BK=32, 4 waves, bf16 MFMA ----------
// Double-buffered K-loop, stage-at-top, counted vmcnt(4), raw barriers.
// Chunk-XOR swizzle: LDS[row][ch] holds global[row][ch ^ (row&3)] (16B
// chunks within the 64B row); staging pre-swizzles the global source,
// fragment reads apply the same XOR. XCD-aware bijective block swizzle.
// MODE 0: t = A@B^T + bias, bf16 store; fused row-norm atomicAdd into s2out
// MODE 1: K = exp(-10*(sqrt(s2+g2-2C)*sw*gw+eps)) bf16 store (batched)
// MODE 2: out = u .* C, fp32 store (batched)
template <int MODE, int GX, int GY>
__global__ __launch_bounds__(256) void gemm_bt_kernel(
    const bf16_t* __restrict__ A, const bf16_t* __restrict__ Bm, int K_len,
    size_t strideAb, size_t strideBb,
    void* __restrict__ outp, size_t strideOb, int ldc,
    const float* __restrict__ bias,
    const float* __restrict__ s2, const float* __restrict__ g2,
    const float* __restrict__ sw, const float* __restrict__ gw,
    const float* __restrict__ uvec, float* __restrict__ s2out) {
  __shared__ bf16_t lds[2][2][128 * 32];   // [buf][A=0/B=1][row*32+col]
  const int nwg = gridDim.x;
  const int lin = blockIdx.x;
  const int lin2 = (lin & 7) * (nwg >> 3) + (lin >> 3);
  const int bx = lin2 % GX;
  const int by = (lin2 / GX) % GY;
  const int bz = lin2 / (GX * GY);
  const int tid = threadIdx.x, lane = tid & 63, wave = tid >> 6;
  const int wr = wave >> 1, wc = wave & 1;
  const bf16_t* Ab = A + (size_t)bz * strideAb;
  const bf16_t* Bb = Bm + (size_t)bz * strideBb;
  const int m0 = by * 128, n0 = bx * 128;
  const int rA = lane >> 2;  // row within 16-row staging group
  // swizzled source chunk: (lane&3) ^ (row&3), row&3 == (lane>>2)&3
  const int c8s = (((lane & 3) ^ (rA & 3))) * 8;

  // stage one 128x32 A-tile + B-tile into lds[buf] (4 gloads per wave);
  // LDS dest linear, global source chunk pre-swizzled
  auto stage = [&](int kt, int buf) {
    #pragma unroll
    for (int c = 0; c < 2; c++) {
      int rg = (c * 4 + wave) * 16;
      async_copy16(Ab + (size_t)(m0 + rg + rA) * K_len + kt + c8s, &lds[buf][0][rg * 32]);
      async_copy16(Bb + (size_t)(n0 + rg + rA) * K_len + kt + c8s, &lds[buf][1][rg * 32]);
    }
  };

  f32x4 acc[4][4];
  #pragma unroll
  for (int i = 0; i < 4; i++)
    #pragma unroll
    for (int j = 0; j < 4; j++) { f32x4 z = {0.f, 0.f, 0.f, 0.f}; acc[i][j] = z; }

  // fragment-read swizzled chunk offset: (lane>>4) ^ (row&3), row&3 == lane&3
  const int chF = ((lane >> 4) ^ (lane & 3)) * 8;
  const int rF = lane & 15;

  stage(0, 0);
  int bufsel = 0;
  for (int kt = 0; kt < K_len; kt += 32) {
    if (kt + 32 < K_len) {
      stage(kt + 32, bufsel ^ 1);                      // next step into other buf
      asm volatile("s_waitcnt vmcnt(4)" ::: "memory"); // wait ONLY current step
    } else {
      asm volatile("s_waitcnt vmcnt(0)" ::: "memory"); // last step: full wait
    }
    __builtin_amdgcn_s_barrier();   // all waves: data ready, prev reads done
    bf16x8 af[4], bf[4];
    #pragma unroll
    for (int m = 0; m < 4; m++)
      af[m] = *(const bf16x8*)&lds[bufsel][0][(wr * 64 + m * 16 + rF) * 32 + chF];
    #pragma unroll
    for (int n = 0; n < 4; n++)
      bf[n] = *(const bf16x8*)&lds[bufsel][1][(wc * 64 + n * 16 + rF) * 32 + chF];
    #pragma unroll
    for (int m = 0; m < 4; m++)
      #pragma unroll
      for (int n = 0; n < 4; n++)
        acc[m][n] = __builtin_amdgcn_mfma_f32_16x16x32_bf16(af[m], bf[n], acc[m][n], 0, 0, 0);
    __builtin_amdgcn_s_barrier();   // reads of lds[bufsel] complete
    bufsel ^= 1;
  }

  // epilogue: C/D frag mapping col=lane&15, row=(lane>>4)*4+j
  const int bo = bz * 512;
  const int row_base = m0 + wr * 64, col_base = n0 + wc * 64;
  const int r_off = (lane >> 4) * 4, c_off = lane & 15;
  float p[4][4];   // MODE0: per-thread row partial sums of (val+bias)^2
  #pragma unroll
  for (int m = 0; m < 4; m++)
    #pragma unroll
    for (int j = 0; j < 4; j++) p[m][j] = 0.f;

  #pragma unroll
  for (int m = 0; m < 4; m++) {
    #pragma unroll
    for (int n = 0; n < 4; n++) {
      #pragma unroll
      for (int j = 0; j < 4; j++) {
        int gm = row_base + m * 16 + r_off + j;
        int gn = col_base + n * 16 + c_off;
        float val = acc[m][n][j];
        if (MODE == 0) {
          float tv = val + bias[gn];
          ((bf16_t*)outp)[(size_t)gm * ldc + gn] = (__bf16)tv;
          p[m][j] += tv * tv;
        } else if (MODE == 1) {
          float sq = s2[bo + gm] + g2[bo + gn] - 2.0f * val;
          float d = sqrtf(fmaxf(sq, 0.0f));
          float cost = d * sw[bo + gm] * gw[bo + gn] + 1e-12f;
          ((bf16_t*)outp + (size_t)bz * strideOb)[(size_t)gm * ldc + gn] =
              (__bf16)expf(-10.0f * cost);
        } else {
          ((float*)outp + (size_t)bz * strideOb)[(size_t)gm * ldc + gn] =
              uvec[bo + gm] * val;
        }
      }
    }
  }

  if (MODE == 0) {
    // reduce (val+bias)^2 across the 128 cols this block owns -> atomicAdd s2out
    __syncthreads();                    // all LDS reads done; reuse lds
    float* lRed = (float*)&lds[0][0][0];  // 128 floats
    #pragma unroll
    for (int m = 0; m < 4; m++)
      #pragma unroll
      for (int j = 0; j < 4; j++) {
        float v = p[m][j];
        v += __shfl_xor(v, 1);
        v += __shfl_xor(v, 2);
        v += __shfl_xor(v, 4);
        v += __shfl_xor(v, 8);
        p[m][j] = v;               // valid at lanes with (lane&15)==0
      }
    int rl = wr * 64 + (lane >> 4) * 4;
    if (wc == 0 && (lane & 15) == 0) {
      #pragma unroll
      for (int m = 0; m < 4; m++)
        #pragma unroll
        for (int j = 0; j < 4; j++) lRed[rl + m * 16 + j] = p[m][j];
    }
    __syncthreads();
    if (wc == 1 && (lane & 15) == 0) {
      #pragma unroll
      for (int m = 0; m < 4; m++)
        #pragma unroll
        for (int j = 0; j < 4; j++)
          atomicAdd(&s2out[m0 + rl + m * 16 + j], lRed[rl + m * 16 + j] + p[m][j]);
    }
  }
}

// ---------- wide transpose: out[c][r] = in[r][c] * (SCALE ? v[r] : 1) ----------
template <int SCALE>
__global__ __launch_bounds__(256) void wide_transpose_kernel(
    const bf16_t* __restrict__ in, bf16_t* __restrict__ out,
    const float* __restrict__ vscale, int inRows, int inCols) {
  __shared__ bf16_t tl[32][66];
  size_t base = (size_t)blockIdx.z * inRows * inCols;
  int r0 = blockIdx.y * 32, c0 = blockIdx.x * 64;
  int row = threadIdx.x >> 3, cc8 = (threadIdx.x & 7) * 8;
  *(bf16x8*)&tl[row][cc8] =
      *(const bf16x8*)(in + base + (size_t)(r0 + row) * inCols + c0 + cc8);
  __syncthreads();
  int orow = threadIdx.x >> 2;
  int rq = (threadIdx.x & 3) * 8;
  bf16x8 o;
  if (SCALE) {
    const float* vp = vscale + (size_t)blockIdx.z * inRows + r0 + rq;
    float4 va = *(const float4*)vp;
    float4 vb = *(const float4*)(vp + 4);
    o[0] = (__bf16)((float)tl[rq + 0][orow] * va.x);
    o[1] = (__bf16)((float)tl[rq + 1][orow] * va.y);
    o[2] = (__bf16)((float)tl[rq + 2][orow] * va.z);
    o[3] = (__bf16)((float)tl[rq + 3][orow] * va.w);
    o[4] = (__bf16)((float)tl[rq + 4][orow] * vb.x);
    o[5] = (__bf16)((float)tl[rq + 5][orow] * vb.y);
    o[6] = (__bf16)((float)tl[rq + 6][orow] * vb.z);
    o[7] = (__bf16)((float)tl[rq + 7][orow] * vb.w);
  } else {
    #pragma unroll
    for (int i = 0; i < 8; i++) o[i] = tl[rq + i][orow];
  }
  *(bf16x8*)(out + base + (size_t)(c0 + orow) * inRows + r0 + rq) = o;
}

// ---------- Sinkhorn half-iteration, grid-wide ----------
template <int INIT>
__global__ __launch_bounds__(256) void sink_pass_kernel(
    const bf16_t* __restrict__ Mmat, const float* __restrict__ x,
    const float* __restrict__ w, float* __restrict__ y) {
  const int b = blockIdx.y;
  const int t = threadIdx.x;
  __shared__ float xs[512];
  if (!INIT) {
    ((float2*)xs)[t] = ((const float2*)(x + b * 512))[t];
    __syncthreads();
  }
  const int row = blockIdx.x * 64 + (t >> 2);
  const int seg = t & 3;
  const bf16_t* rp = Mmat + ((size_t)b * 512 + row) * 512;
  float sum = 0.f;
  #pragma unroll
  for (int j = 0; j < 16; j++) {
    bf16x8 kv = *(const bf16x8*)(rp + seg * 8 + j * 32);
    if (INIT) {
      sum += (float)kv[0] + (float)kv[1] + (float)kv[2] + (float)kv[3] +
             (float)kv[4] + (float)kv[5] + (float)kv[6] + (float)kv[7];
    } else {
      const float4* xp = (const float4*)&xs[seg * 8 + j * 32];
      float4 x0 = xp[0], x1 = xp[1];
      sum += (float)kv[0] * x0.x + (float)kv[1] * x0.y + (float)kv[2] * x0.z +
             (float)kv[3] * x0.w + (float)kv[4] * x1.x + (float)kv[5] * x1.y +
             (float)kv[6] * x1.z + (float)kv[7] * x1.w;
    }
  }
  if (INIT) sum *= (1.0f / 512.0f);
  sum += __shfl_xor(sum, 1);
  sum += __shfl_xor(sum, 2);
  if (seg == 0)
    y[b * 512 + row] = powf(w[b * 512 + row] / sum, 10.0f / 10.1f);
}

// ---------- Sinkhorn closed-form extrapolation to iteration 100 ----------
// args: (prev u, curr u, prev v, curr v); x_100 = x_M * exp(rho_M * G)
__global__ __launch_bounds__(512) void sink_final_kernel(
    const float* __restrict__ ua, const float* __restrict__ ub,
    const float* __restrict__ va, const float* __restrict__ vb,
    float* __restrict__ u_out, float* __restrict__ v_out, float Gf) {
  const int b = blockIdx.x, t = threadIdx.x, idx = b * 512 + t;
  const float ubv = ub[idx], vbv = vb[idx];
  float su = logf(ubv / ua[idx]);
  float sv = logf(vbv / va[idx]);
  #pragma unroll
  for (int ofs = 32; ofs > 0; ofs >>= 1) {
    su += __shfl_down(su, ofs);
    sv += __shfl_down(sv, ofs);
  }
  __shared__ float r0[8], r1[8];
  __shared__ float mu, mv;
  if ((t & 63) == 0) { r0[t >> 6] = su; r1[t >> 6] = sv; }
  __syncthreads();
  if (t == 0) {
    float a = 0.f, c = 0.f;
    #pragma unroll
    for (int i = 0; i < 8; i++) { a += r0[i]; c += r1[i]; }
    mu = a / 512.f; mv = c / 512.f;
  }
  __syncthreads();
  u_out[idx] = ubv * expf(Gf * mu);
  v_out[idx] = vbv * expf(Gf * mv);
}

extern "C" void kernel_launch(void* const* d_in, const int* in_sizes, int n_in,
                              void* d_out, int out_size, void* d_ws, size_t ws_size,
                              hipStream_t stream) {
  (void)in_sizes; (void)n_in; (void)out_size; (void)ws_size;
  const float* src = (const float*)d_in[0];   // [32,512,1024]
  const float* tgt = (const float*)d_in[1];   // [32,512,1024]
  const int* smask = (const int*)d_in[2];     // [32,512]
  const int* gmask = (const int*)d_in[3];     // [32,512]
  const float* W   = (const float*)d_in[4];   // [1024,1024]
  const float* bias = (const float*)d_in[5];  // [1024]
  float* out = (float*)d_out;                 // [32,512,1024]

  uint8_t* ws = (uint8_t*)d_ws;
  bf16_t* s_bf  = (bf16_t*)(ws + 0);          // 32 MB
  bf16_t* Kmat  = (bf16_t*)(ws + 0);          // reuse after gemm1: 16 MB
  bf16_t* KTmat = (bf16_t*)(ws + 16777216);   // 16 MB
  bf16_t* W_bf  = (bf16_t*)(ws + 33554432);   // 2 MB
  float* ua = (float*)(ws + 33554432);        // overwrite W_bf after gemm1
  float* ub = ua + 16384;
  float* va = ub + 16384;
  float* vb = va + 16384;
  bf16_t* g_bf  = (bf16_t*)(ws + 35651584);   // 32 MB
  bf16_t* t_bf  = (bf16_t*)(ws + 69206016);   // 32 MB
  bf16_t* gTv   = (bf16_t*)(ws + 69206016);   // reuse after gemm2
  float* s2  = (float*)(ws + 102760448);
  float* g2  = s2 + 16384;
  float* swv = g2 + 16384;
  float* gwv = swv + 16384;
  float* uv  = gwv + 16384;
  float* vv  = uv + 16384;

  // 1. conversions + g norms; zero s2 for fused-norm atomics
  cvt2_kernel<<<8704, 256, 0, stream>>>(src, s_bf, 2097152, W, W_bf);
  prep_g_kernel<<<16384, 128, 0, stream>>>(tgt, g_bf, g2);
  hipMemsetAsync(s2, 0, 16384 * sizeof(float), stream);

  // 2. t = s @ W^T + b  (M=16384,N=1024,K=1024) + fused row norms -> s2
  gemm_bt_kernel<0, 8, 128><<<1024, 256, 0, stream>>>(
      s_bf, W_bf, 1024, 0, 0, t_bf, 0, 1024, bias,
      nullptr, nullptr, nullptr, nullptr, nullptr, s2);

  // 3. weights (both sides, one dispatch)
  weights2_kernel<<<64, 512, 0, stream>>>(s2, smask, swv, g2, gmask, gwv);

  // 4. K = exp(-10*cost)  (per batch 512x512, K=1024)
  gemm_bt_kernel<1, 4, 4><<<512, 256, 0, stream>>>(
      t_bf, g_bf, 1024, (size_t)512 * 1024, (size_t)512 * 1024,
      Kmat, (size_t)512 * 512, 512, nullptr, s2, g2, swv, gwv, nullptr, nullptr);

  // 5. K^T (wide transpose)
  wide_transpose_kernel<0><<<dim3(8, 16, 32), 256, 0, stream>>>(
      Kmat, KTmat, nullptr, NS, NG);

  // 6. Sinkhorn: 2 real iterations (4 passes) + extrapolation.
  // u1->ua v1->va u2->ub v2->vb; ratios (prev=ua,curr=ub),(va,vb).
  dim3 pg(NS / 64, NBATCH);
  sink_pass_kernel<1><<<pg, 256, 0, stream>>>(Kmat, nullptr, swv, ua);   // u1
  sink_pass_kernel<0><<<pg, 256, 0, stream>>>(KTmat, ua, gwv, va);       // v1
  sink_pass_kernel<0><<<pg, 256, 0, stream>>>(Kmat, va, swv, ub);        // u2
  sink_pass_kernel<0><<<pg, 256, 0, stream>>>(KTmat, ub, gwv, vb);       // v2

  // G = sum_{j=1}^{100-M_REAL} fi^(2j) in double
  double fi2 = (10.0 / 10.1) * (10.0 / 10.1);
  double Gd = 0.0, pd = 1.0;
  for (int j = 0; j < (N_TOT - M_REAL); j++) { pd *= fi2; Gd += pd; }
  sink_final_kernel<<<32, 512, 0, stream>>>(ua, ub, va, vb, uv, vv, (float)Gd);

  // 7. gTv[h][g] = v[g]*g[g][h] (wide transpose + scale)
  wide_transpose_kernel<1><<<dim3(16, 16, 32), 256, 0, stream>>>(
      g_bf, gTv, vv, NG, NH);

  // 8. aligned = u .* (K @ gTv)  (per batch 512x1024, K=512)
  gemm_bt_kernel<2, 8, 4><<<1024, 256, 0, stream>>>(
      Kmat, gTv, 512, (size_t)512 * 512, (size_t)1024 * 512,
      out, (size_t)512 * 1024, 1024, nullptr, nullptr, nullptr, nullptr, nullptr, uv, nullptr);
}